// Round 18
// baseline (409.226 us; speedup 1.0000x reference)
//
#include <hip/hip_runtime.h>
#include <hip/hip_fp16.h>

// EMD approx-match (auction) + match_cost. [B,N,M] match never materialized.
// 12 dispatches: memset, A0', CA'0..8 (B folded via cross-kernel t1 shadow
// atomics), C9. R18 = R17 math with CHUNKED staging (2x1024 pts, ~17KB LDS)
// + __launch_bounds__(256,8) -> 8 blocks/CU = 32 waves/CU (2x R14). Clean
// occupancy experiment: R15's version conflated occupancy with 2x atomic
// traffic + 4/8-way LDS conflict maps; here blocks/grid/lane-maps/atomics
// are IDENTICAL to R17 (conflict profile unchanged), only LDS size halves.
// sweep2 restages coords (w unused). Issue floor ~128us vs observed 357
// (36% efficiency, VALUBusy 17.5% in R15) -- testing the stall=latency
// hypothesis with 2x waves/SIMD.

#define BATCH 8
#define NPTS 2048
#define MPTS 2048
#define BLOCK 256
#define ROWS 16
#define CHUNK 1024
#define NSH 8  // t1 shadow copies
#define LOG2E 1.44269504088896340736f

__device__ __forceinline__ float fast_exp2(float x) {
  return __builtin_amdgcn_exp2f(x);
}
__device__ __forceinline__ float fast_sqrt(float a) {
  return __builtin_amdgcn_sqrtf(a);
}
__device__ __forceinline__ float packh2(float c, float r) {
  __half2 h = __halves2half2(__float2half_rn(c), __float2half_rn(r));
  return __builtin_bit_cast(float, h);
}

// Load 8 consecutive points (r0 multiple of 4) as 6 float4s, scaled by k.
__device__ __forceinline__ void load8(const float4* q, int r0, float k,
                                      float* x, float* y, float* z) {
  int b4 = (r0 >> 2) * 3;
  float4 q0 = q[b4], q1 = q[b4 + 1], q2 = q[b4 + 2];
  float4 q3 = q[b4 + 3], q4 = q[b4 + 4], q5 = q[b4 + 5];
  x[0] = k * q0.x; y[0] = k * q0.y; z[0] = k * q0.z;
  x[1] = k * q0.w; y[1] = k * q1.x; z[1] = k * q1.y;
  x[2] = k * q1.z; y[2] = k * q1.w; z[2] = k * q2.x;
  x[3] = k * q2.y; y[3] = k * q2.z; z[3] = k * q2.w;
  x[4] = k * q3.x; y[4] = k * q3.y; z[4] = k * q3.z;
  x[5] = k * q3.w; y[5] = k * q4.x; z[5] = k * q4.y;
  x[6] = k * q4.z; y[6] = k * q4.w; z[6] = k * q5.x;
  x[7] = k * q5.y; y[7] = k * q5.z; z[7] = k * q5.w;
}

// ---------------------------------------------------------------------------
// A0': rowscale_0 = 1/(sum_m exp(lvl0*d2)+1e-9); sweep2 atomicAdds t1_0 into
// shadow copy (blk&7). Blocks blk<8 zero one copy each of t1zero.
__global__ __launch_bounds__(BLOCK, 8) void emd_A0_kernel(
    const float* __restrict__ xyz1, const float* __restrict__ xyz2,
    float* __restrict__ rowscale, float* __restrict__ out,
    float* __restrict__ t9, float* __restrict__ t1acc,
    float* __restrict__ t1zero, float k0) {
  __shared__ float4 sP[CHUNK];
  __shared__ float sRed[ROWS * 4];
  __shared__ float sRs[ROWS];

  const int tid = threadIdx.x;
  const int bid = blockIdx.x;
  const int b = bid >> 7;
  const int blk = bid & 127;
  const int t0 = blk * ROWS;
  if (bid == 0 && tid < BATCH) { out[tid] = 0.0f; t9[tid] = 0.0f; }

  const int wave = tid >> 6, lane = tid & 63;
  const int phase = lane >> 1, rg = lane & 1;
  const int r0 = t0 + rg * 8;
  const float4* q2 = (const float4*)(xyz2 + (size_t)b * MPTS * 3);
  float4* z4 = (blk < NSH)
      ? (float4*)(t1zero + ((size_t)blk * BATCH + b) * MPTS) : nullptr;

  float x1[8], y1[8], z1[8], acc[8];
  load8((const float4*)(xyz1 + (size_t)b * NPTS * 3), r0, k0, x1, y1, z1);
#pragma unroll
  for (int j = 0; j < 8; ++j) acc[j] = 0.0f;
  const int mb = wave * 256 + phase;

  for (int ch = 0; ch < 2; ++ch) {
    __syncthreads();
    {
      const float4* qc = q2 + ch * 768;     // 1024 pts = 768 float4
      int g = tid;
      float4 a = qc[3 * g], bb = qc[3 * g + 1], c = qc[3 * g + 2];
      sP[4 * g + 0] = make_float4(k0 * a.x, k0 * a.y, k0 * a.z, 0.0f);
      sP[4 * g + 1] = make_float4(k0 * a.w, k0 * bb.x, k0 * bb.y, 0.0f);
      sP[4 * g + 2] = make_float4(k0 * bb.z, k0 * bb.w, k0 * c.x, 0.0f);
      sP[4 * g + 3] = make_float4(k0 * c.y, k0 * c.z, k0 * c.w, 0.0f);
      if (z4) z4[ch * 256 + g] = make_float4(0.f, 0.f, 0.f, 0.f);
    }
    __syncthreads();
#pragma unroll 2
    for (int it = 0; it < 8; ++it) {
      float4 v = sP[mb + it * 32];
#pragma unroll
      for (int j = 0; j < 8; ++j) {
        float dx = x1[j] - v.x, dy = y1[j] - v.y, dz = z1[j] - v.z;
        float s = __builtin_fmaf(dx, dx, __builtin_fmaf(dy, dy, dz * dz));
        acc[j] += fast_exp2(-s);
      }
    }
  }
#pragma unroll
  for (int j = 0; j < 8; ++j) {
    acc[j] += __shfl_xor(acc[j], 2, 64);
    acc[j] += __shfl_xor(acc[j], 4, 64);
    acc[j] += __shfl_xor(acc[j], 8, 64);
    acc[j] += __shfl_xor(acc[j], 16, 64);
    acc[j] += __shfl_xor(acc[j], 32, 64);
  }
  if (lane < 2) {
#pragma unroll
    for (int j = 0; j < 8; ++j) sRed[(rg * 8 + j) * 4 + wave] = acc[j];
  }
  __syncthreads();
  if (tid < ROWS) {
    float s = sRed[tid * 4] + sRed[tid * 4 + 1] + sRed[tid * 4 + 2] +
              sRed[tid * 4 + 3];
    float rs = 1.0f / (s + 1e-9f);
    rowscale[(size_t)b * NPTS + t0 + tid] = rs;
    sRs[tid] = rs;
  }
  __syncthreads();

  // sweep2: t1_0 partials -> shadow-copy atomics (restage chunks)
  float rsn[8];
#pragma unroll
  for (int j = 0; j < 8; ++j) rsn[j] = sRs[rg * 8 + j];
  float* accb = t1acc + ((size_t)(blk & (NSH - 1)) * BATCH + b) * MPTS;
  for (int ch = 0; ch < 2; ++ch) {
    __syncthreads();
    {
      const float4* qc = q2 + ch * 768;
      int g = tid;
      float4 a = qc[3 * g], bb = qc[3 * g + 1], c = qc[3 * g + 2];
      sP[4 * g + 0] = make_float4(k0 * a.x, k0 * a.y, k0 * a.z, 0.0f);
      sP[4 * g + 1] = make_float4(k0 * a.w, k0 * bb.x, k0 * bb.y, 0.0f);
      sP[4 * g + 2] = make_float4(k0 * bb.z, k0 * bb.w, k0 * c.x, 0.0f);
      sP[4 * g + 3] = make_float4(k0 * c.y, k0 * c.z, k0 * c.w, 0.0f);
    }
    __syncthreads();
#pragma unroll 2
    for (int it = 0; it < 8; ++it) {
      int idx = mb + it * 32;
      float4 v = sP[idx];
      float part = 0.0f;
#pragma unroll
      for (int j = 0; j < 8; ++j) {
        float dx = x1[j] - v.x, dy = y1[j] - v.y, dz = z1[j] - v.z;
        float s = __builtin_fmaf(dx, dx, __builtin_fmaf(dy, dy, dz * dz));
        part = __builtin_fmaf(fast_exp2(-s), rsn[j], part);
      }
      part += __shfl_xor(part, 1, 64);
      if (rg == 0) atomicAdd(accb + ch * CHUNK + idx, part);
    }
  }
}

// ---------------------------------------------------------------------------
// CA'(l): staging sums 8 t1 shadow copies + former-B clipping (desig block
// writes rrOut; blocks blk<8 zero t1Zero copies); sweep1 = cost + remainL +
// rowscale(l+1) (e1=e2^4); sweep2 atomicAdds t1_{l+1} (restaged coords).
// LAST: e1=exp2(-s), t9 += sum rsN, no sweep2.
template <bool FIRST, bool LAST>
__global__ __launch_bounds__(BLOCK, 8) void emd_CA_kernel(
    const float* __restrict__ xyz1, const float* __restrict__ xyz2,
    float* __restrict__ rowscale, float* __restrict__ remainL,
    const float* __restrict__ rrIn, float* __restrict__ rrOut,
    const float* __restrict__ t1In, float* __restrict__ t1Acc,
    float* __restrict__ t1Zero, float* __restrict__ out,
    float* __restrict__ t9, float kS, float invK) {
  __shared__ float4 sP[CHUNK];
  __shared__ float sRedS[ROWS * 4];
  __shared__ float sRedC[ROWS * 4];
  __shared__ float sRedR[ROWS * 4];
  __shared__ float sCost[ROWS];
  __shared__ float sRs[ROWS];

  const int tid = threadIdx.x;
  const int bid = blockIdx.x;
  const int b = bid >> 7;
  const int blk = bid & 127;
  const int t0 = blk * ROWS;
  const bool desig = blk == 0;
  const int wave = tid >> 6, lane = tid & 63;
  const int phase = lane >> 2, rg = lane & 3;
  const int r0 = t0 + rg * 4;

  const float4* q2 = (const float4*)(xyz2 + (size_t)b * MPTS * 3);
  const float4* rr4 = (const float4*)(rrIn + (size_t)b * MPTS);
  const float4* t14 = (const float4*)(t1In + (size_t)b * MPTS);
  const size_t sh4 = (size_t)BATCH * MPTS / 4;
  float4* ro4 = (float4*)(rrOut + (size_t)b * MPTS);
  float4* z4 = (!LAST && blk < NSH)
      ? (float4*)(t1Zero + ((size_t)blk * BATCH + b) * MPTS) : nullptr;

  float x1[4], y1[4], z1[4];
  {
    const float4* q1 = (const float4*)(xyz1 + (size_t)b * NPTS * 3);
    int b4 = (r0 >> 2) * 3;
    float4 a = q1[b4], bb = q1[b4 + 1], c = q1[b4 + 2];
    x1[0] = kS * a.x;  y1[0] = kS * a.y;  z1[0] = kS * a.z;
    x1[1] = kS * a.w;  y1[1] = kS * bb.x; z1[1] = kS * bb.y;
    x1[2] = kS * bb.z; y1[2] = kS * bb.w; z1[2] = kS * c.x;
    x1[3] = kS * c.y;  y1[3] = kS * c.z;  z1[3] = kS * c.w;
  }
  float accS[4] = {0.f, 0.f, 0.f, 0.f};
  float accC[4] = {0.f, 0.f, 0.f, 0.f};
  float accR[4] = {0.f, 0.f, 0.f, 0.f};
  const int mb = wave * 256 + phase;

  for (int ch = 0; ch < 2; ++ch) {
    __syncthreads();
    {
      const float4* qc = q2 + ch * 768;
      int g = tid;
      float4 a = qc[3 * g], bb = qc[3 * g + 1], c = qc[3 * g + 2];
      float4 t1v = t14[ch * 256 + g];
#pragma unroll
      for (int cpy = 1; cpy < NSH; ++cpy) {
        float4 tv = t14[cpy * sh4 + ch * 256 + g];
        t1v.x += tv.x; t1v.y += tv.y; t1v.z += tv.z; t1v.w += tv.w;
      }
      float4 rrv = FIRST ? make_float4(1.f, 1.f, 1.f, 1.f) : rr4[ch * 256 + g];
      float cc[4], rn[4];
      float rrc[4] = {rrv.x, rrv.y, rrv.z, rrv.w};
      float t1c[4] = {t1v.x, t1v.y, t1v.z, t1v.w};
#pragma unroll
      for (int i = 0; i < 4; ++i) {
        float colsum = rrc[i] * t1c[i];
        float cs = fminf(rrc[i] / (colsum + 1e-9f), 1.0f);
        cc[i] = rrc[i] * cs;
        rn[i] = fmaxf(rrc[i] - colsum * cs, 0.0f);
      }
      sP[4 * g + 0] = make_float4(kS * a.x, kS * a.y, kS * a.z, packh2(cc[0], rn[0]));
      sP[4 * g + 1] = make_float4(kS * a.w, kS * bb.x, kS * bb.y, packh2(cc[1], rn[1]));
      sP[4 * g + 2] = make_float4(kS * bb.z, kS * bb.w, kS * c.x, packh2(cc[2], rn[2]));
      sP[4 * g + 3] = make_float4(kS * c.y, kS * c.z, kS * c.w, packh2(cc[3], rn[3]));
      if (desig) ro4[ch * 256 + g] = make_float4(rn[0], rn[1], rn[2], rn[3]);
      if (z4) z4[ch * 256 + g] = make_float4(0.f, 0.f, 0.f, 0.f);
    }
    __syncthreads();
#pragma unroll 4
    for (int it = 0; it < 16; ++it) {
      float4 v = sP[mb + it * 16];
      __half2 h = __builtin_bit_cast(__half2, v.w);
      float cc = __low2float(h);
      float rr = __high2float(h);
#pragma unroll
      for (int j = 0; j < 4; ++j) {
        float dx = x1[j] - v.x, dy = y1[j] - v.y, dz = z1[j] - v.z;
        float s = __builtin_fmaf(dx, dx, __builtin_fmaf(dy, dy, dz * dz));
        float sq = fast_sqrt(s);
        float e1, e2;
        if (LAST) {
          e2 = 1.0f;
          e1 = fast_exp2(-s);
        } else {
          e2 = fast_exp2(-s);
          float e2s = e2 * e2;
          e1 = e2s * e2s;
        }
        float t = e1 * cc;
        accS[j] += t;
        accC[j] = __builtin_fmaf(t, sq, accC[j]);
        if (LAST) accR[j] += rr;
        else      accR[j] = __builtin_fmaf(e2, rr, accR[j]);
      }
    }
  }
#pragma unroll
  for (int j = 0; j < 4; ++j) {
    accS[j] += __shfl_xor(accS[j], 4, 64);
    accS[j] += __shfl_xor(accS[j], 8, 64);
    accS[j] += __shfl_xor(accS[j], 16, 64);
    accS[j] += __shfl_xor(accS[j], 32, 64);
    accC[j] += __shfl_xor(accC[j], 4, 64);
    accC[j] += __shfl_xor(accC[j], 8, 64);
    accC[j] += __shfl_xor(accC[j], 16, 64);
    accC[j] += __shfl_xor(accC[j], 32, 64);
    accR[j] += __shfl_xor(accR[j], 4, 64);
    accR[j] += __shfl_xor(accR[j], 8, 64);
    accR[j] += __shfl_xor(accR[j], 16, 64);
    accR[j] += __shfl_xor(accR[j], 32, 64);
  }
  if (lane < 4) {
#pragma unroll
    for (int j = 0; j < 4; ++j) {
      sRedS[(rg * 4 + j) * 4 + wave] = accS[j];
      sRedC[(rg * 4 + j) * 4 + wave] = accC[j];
      sRedR[(rg * 4 + j) * 4 + wave] = accR[j];
    }
  }
  __syncthreads();
  if (tid < ROWS) {
    float S2 = sRedS[tid * 4] + sRedS[tid * 4 + 1] + sRedS[tid * 4 + 2] +
               sRedS[tid * 4 + 3];
    float C = sRedC[tid * 4] + sRedC[tid * 4 + 1] + sRedC[tid * 4 + 2] +
              sRedC[tid * 4 + 3];
    float R = sRedR[tid * 4] + sRedR[tid * 4 + 1] + sRedR[tid * 4 + 2] +
              sRedR[tid * 4 + 3];
    size_t idx = (size_t)b * NPTS + t0 + tid;
    float rs = rowscale[idx];
    float rl = FIRST ? 1.0f : remainL[idx];
    float rlN = fmaxf(rl - rs * S2, 0.0f);
    remainL[idx] = rlN;
    float rsN = rlN / (R + 1e-9f);
    rowscale[idx] = rsN;
    sCost[tid] = rs * C * invK;
    sRs[tid] = rsN;
  }
  __syncthreads();
  if (tid == 0) {
    float t = 0.0f;
#pragma unroll
    for (int i = 0; i < ROWS; ++i) t += sCost[i];
    atomicAdd(out + b, t);
    if (LAST) {
      float r = 0.0f;
#pragma unroll
      for (int i = 0; i < ROWS; ++i) r += sRs[i];
      atomicAdd(t9 + b, r);
    }
  }
  if (!LAST) {
    // sweep2: t1_{l+1} partials (restage coords only; .w unused)
    float rsn[4];
#pragma unroll
    for (int j = 0; j < 4; ++j) rsn[j] = sRs[rg * 4 + j];
    float* accb = t1Acc + ((size_t)(blk & (NSH - 1)) * BATCH + b) * MPTS;
    for (int ch = 0; ch < 2; ++ch) {
      __syncthreads();
      {
        const float4* qc = q2 + ch * 768;
        int g = tid;
        float4 a = qc[3 * g], bb = qc[3 * g + 1], c = qc[3 * g + 2];
        sP[4 * g + 0] = make_float4(kS * a.x, kS * a.y, kS * a.z, 0.0f);
        sP[4 * g + 1] = make_float4(kS * a.w, kS * bb.x, kS * bb.y, 0.0f);
        sP[4 * g + 2] = make_float4(kS * bb.z, kS * bb.w, kS * c.x, 0.0f);
        sP[4 * g + 3] = make_float4(kS * c.y, kS * c.z, kS * c.w, 0.0f);
      }
      __syncthreads();
#pragma unroll 4
      for (int it = 0; it < 16; ++it) {
        int idx = mb + it * 16;
        float4 v = sP[idx];
        float part = 0.0f;
#pragma unroll
        for (int j = 0; j < 4; ++j) {
          float dx = x1[j] - v.x, dy = y1[j] - v.y, dz = z1[j] - v.z;
          float s = __builtin_fmaf(dx, dx, __builtin_fmaf(dy, dy, dz * dz));
          part = __builtin_fmaf(fast_exp2(-s), rsn[j], part);
        }
        part += __shfl_xor(part, 1, 64);
        part += __shfl_xor(part, 2, 64);
        if (rg == 0) atomicAdd(accb + ch * CHUNK + idx, part);
      }
    }
  }
}

// ---------------------------------------------------------------------------
// C9 (lvl=0): t1 = t9[b]; colcoef during staging; cost += rs * sum cc*sqrt(d2).
__global__ __launch_bounds__(BLOCK, 8) void emd_C9_kernel(
    const float* __restrict__ xyz1, const float* __restrict__ xyz2,
    const float* __restrict__ rowscale, const float* __restrict__ remainR,
    const float* __restrict__ t9, float* __restrict__ out) {
  __shared__ float4 sP[CHUNK];
  __shared__ float sRed[ROWS * 4];
  __shared__ float sCost[ROWS];

  const int tid = threadIdx.x;
  const int bid = blockIdx.x;
  const int b = bid >> 7;
  const int t0 = (bid & 127) * ROWS;
  const int wave = tid >> 6, lane = tid & 63;
  const int phase = lane >> 1, rg = lane & 1;
  const int r0 = t0 + rg * 8;
  const float t1 = t9[b];

  const float4* q2 = (const float4*)(xyz2 + (size_t)b * MPTS * 3);
  const float4* rr4 = (const float4*)(remainR + (size_t)b * MPTS);

  float x1[8], y1[8], z1[8], acc[8];
  load8((const float4*)(xyz1 + (size_t)b * NPTS * 3), r0, 1.0f, x1, y1, z1);
#pragma unroll
  for (int j = 0; j < 8; ++j) acc[j] = 0.0f;
  const int mb = wave * 256 + phase;

  for (int ch = 0; ch < 2; ++ch) {
    __syncthreads();
    {
      const float4* qc = q2 + ch * 768;
      int g = tid;
      float4 a = qc[3 * g], bb = qc[3 * g + 1], c = qc[3 * g + 2];
      float4 rr = rr4[ch * 256 + g];
      float w0 = rr.x * fminf(rr.x / (rr.x * t1 + 1e-9f), 1.0f);
      float w1 = rr.y * fminf(rr.y / (rr.y * t1 + 1e-9f), 1.0f);
      float w2 = rr.z * fminf(rr.z / (rr.z * t1 + 1e-9f), 1.0f);
      float w3 = rr.w * fminf(rr.w / (rr.w * t1 + 1e-9f), 1.0f);
      sP[4 * g + 0] = make_float4(a.x, a.y, a.z, w0);
      sP[4 * g + 1] = make_float4(a.w, bb.x, bb.y, w1);
      sP[4 * g + 2] = make_float4(bb.z, bb.w, c.x, w2);
      sP[4 * g + 3] = make_float4(c.y, c.z, c.w, w3);
    }
    __syncthreads();
#pragma unroll 2
    for (int it = 0; it < 8; ++it) {
      float4 v = sP[mb + it * 32];
#pragma unroll
      for (int j = 0; j < 8; ++j) {
        float dx = x1[j] - v.x, dy = y1[j] - v.y, dz = z1[j] - v.z;
        float d2 = __builtin_fmaf(dx, dx, __builtin_fmaf(dy, dy, dz * dz));
        acc[j] = __builtin_fmaf(fast_sqrt(d2), v.w, acc[j]);
      }
    }
  }
#pragma unroll
  for (int j = 0; j < 8; ++j) {
    acc[j] += __shfl_xor(acc[j], 2, 64);
    acc[j] += __shfl_xor(acc[j], 4, 64);
    acc[j] += __shfl_xor(acc[j], 8, 64);
    acc[j] += __shfl_xor(acc[j], 16, 64);
    acc[j] += __shfl_xor(acc[j], 32, 64);
  }
  if (lane < 2) {
#pragma unroll
    for (int j = 0; j < 8; ++j) sRed[(rg * 8 + j) * 4 + wave] = acc[j];
  }
  __syncthreads();
  if (tid < ROWS) {
    float C = sRed[tid * 4] + sRed[tid * 4 + 1] + sRed[tid * 4 + 2] +
              sRed[tid * 4 + 3];
    sCost[tid] = rowscale[(size_t)b * NPTS + t0 + tid] * C;
  }
  __syncthreads();
  if (tid == 0) {
    float t = 0.0f;
#pragma unroll
    for (int i = 0; i < ROWS; ++i) t += sCost[i];
    atomicAdd(out + b, t);
  }
}

// ---------------------------------------------------------------------------
extern "C" void kernel_launch(void* const* d_in, const int* in_sizes, int n_in,
                              void* d_out, int out_size, void* d_ws, size_t ws_size,
                              hipStream_t stream) {
  const float* xyz1 = (const float*)d_in[0];
  const float* xyz2 = (const float*)d_in[1];
  float* out = (float*)d_out;
  float* ws = (float*)d_ws;

  const int BN = BATCH * NPTS, BM = BATCH * MPTS;
  const size_t TBUF = (size_t)NSH * BM;
  float* remainL  = ws;
  float* rowscale = ws + BN;
  float* rrA      = ws + 2 * BN;
  float* rrB      = ws + 2 * BN + BM;
  float* t1b      = ws + 2 * BN + 2 * BM;
  float* t9       = ws + 2 * BN + 2 * BM + 3 * TBUF;

  const float levels[9] = {-16384.f, -4096.f, -1024.f, -256.f, -64.f,
                           -16.f,    -4.f,    -1.f,    -0.25f};
  dim3 grid(BATCH * (NPTS / ROWS));  // 1024 blocks

  hipMemsetAsync(t1b, 0, TBUF * sizeof(float), stream);  // zero buf0

  emd_A0_kernel<<<grid, BLOCK, 0, stream>>>(
      xyz1, xyz2, rowscale, out, t9, t1b, t1b + TBUF,
      sqrtf(-levels[0] * LOG2E));

  for (int l = 0; l < 9; ++l) {
    float kB = sqrtf(-levels[l] * LOG2E);
    float kA = 0.5f * kB;
    float* cur = t1b + (size_t)(l % 3) * TBUF;
    float* nxt = t1b + (size_t)((l + 1) % 3) * TBUF;
    float* zer = t1b + (size_t)((l + 2) % 3) * TBUF;
    float* rin = (l % 2 == 0) ? rrA : rrB;  // unused for l==0
    float* rou = (l % 2 == 0) ? rrB : rrA;
    if (l == 0) {
      emd_CA_kernel<true, false><<<grid, BLOCK, 0, stream>>>(
          xyz1, xyz2, rowscale, remainL, rin, rou, cur, nxt, zer, out, t9,
          kA, 1.0f / kA);
    } else if (l < 8) {
      emd_CA_kernel<false, false><<<grid, BLOCK, 0, stream>>>(
          xyz1, xyz2, rowscale, remainL, rin, rou, cur, nxt, zer, out, t9,
          kA, 1.0f / kA);
    } else {
      emd_CA_kernel<false, true><<<grid, BLOCK, 0, stream>>>(
          xyz1, xyz2, rowscale, remainL, rin, rou, cur, nxt, zer, out, t9,
          kB, 1.0f / kB);
    }
  }
  // rr_9 in rrB (l=8 even). t1_9 scalar in t9.
  emd_C9_kernel<<<grid, BLOCK, 0, stream>>>(xyz1, xyz2, rowscale, rrB, t9, out);
}

// Round 19
// 357.449 us; speedup vs baseline: 1.1449x; 1.1449x over previous
//
#include <hip/hip_runtime.h>
#include <hip/hip_fp16.h>

// EMD approx-match (auction) + match_cost. [B,N,M] match never materialized.
// 12 dispatches: memset, A0', CA'0..8 (B folded via cross-kernel t1 shadow
// atomics), C9. R19 = R17 verbatim (the measured optimum, 358us).
// R18 post-mortem: grid 1024 x 256thr = 4096 waves = 4 blocks/CU hard cap --
// launch_bounds(,8) cannot raise occupancy; chunked staging only added
// barrier phases (+7us/CA, 409us total). Plateau record: R14 357 / R17 358
// vs failed departures 368 (R13), 409 (R18), 469 (R16), 1131 (R15).

#define BATCH 8
#define NPTS 2048
#define MPTS 2048
#define BLOCK 256
#define ROWS 16
#define NSH 8  // t1 shadow copies
#define LOG2E 1.44269504088896340736f

__device__ __forceinline__ float fast_exp2(float x) {
  return __builtin_amdgcn_exp2f(x);
}
__device__ __forceinline__ float fast_sqrt(float a) {
  return __builtin_amdgcn_sqrtf(a);
}
__device__ __forceinline__ float packh2(float c, float r) {
  __half2 h = __halves2half2(__float2half_rn(c), __float2half_rn(r));
  return __builtin_bit_cast(float, h);
}

// Load 8 consecutive points (r0 multiple of 4) as 6 float4s, scaled by k.
__device__ __forceinline__ void load8(const float4* q, int r0, float k,
                                      float* x, float* y, float* z) {
  int b4 = (r0 >> 2) * 3;
  float4 q0 = q[b4], q1 = q[b4 + 1], q2 = q[b4 + 2];
  float4 q3 = q[b4 + 3], q4 = q[b4 + 4], q5 = q[b4 + 5];
  x[0] = k * q0.x; y[0] = k * q0.y; z[0] = k * q0.z;
  x[1] = k * q0.w; y[1] = k * q1.x; z[1] = k * q1.y;
  x[2] = k * q1.z; y[2] = k * q1.w; z[2] = k * q2.x;
  x[3] = k * q2.y; y[3] = k * q2.z; z[3] = k * q2.w;
  x[4] = k * q3.x; y[4] = k * q3.y; z[4] = k * q3.z;
  x[5] = k * q3.w; y[5] = k * q4.x; z[5] = k * q4.y;
  x[6] = k * q4.z; y[6] = k * q4.w; z[6] = k * q5.x;
  x[7] = k * q5.y; y[7] = k * q5.z; z[7] = k * q5.w;
}

// ---------------------------------------------------------------------------
// A0': rowscale_0 = 1/(sum_m exp(lvl0*d2)+1e-9); sweep2 atomicAdds t1_0 into
// shadow copy (blk&7) of t1acc (pre-zeroed by memset). Blocks blk<8 zero one
// copy each of t1zero (CA'0's accumulation target).
__global__ __launch_bounds__(BLOCK, 4) void emd_A0_kernel(
    const float* __restrict__ xyz1, const float* __restrict__ xyz2,
    float* __restrict__ rowscale, float* __restrict__ out,
    float* __restrict__ t9, float* __restrict__ t1acc,
    float* __restrict__ t1zero, float k0) {
  __shared__ float4 sP[MPTS];
  __shared__ float sRed[ROWS * 4];
  __shared__ float sRs[ROWS];

  const int tid = threadIdx.x;
  const int bid = blockIdx.x;
  const int b = bid >> 7;
  const int blk = bid & 127;
  const int t0 = blk * ROWS;
  if (bid == 0 && tid < BATCH) { out[tid] = 0.0f; t9[tid] = 0.0f; }

  const float4* q2 = (const float4*)(xyz2 + (size_t)b * MPTS * 3);
  float4* z4 = (blk < NSH)
      ? (float4*)(t1zero + ((size_t)blk * BATCH + b) * MPTS) : nullptr;
  for (int g = tid; g < MPTS / 4; g += BLOCK) {
    float4 a = q2[3 * g], bb = q2[3 * g + 1], c = q2[3 * g + 2];
    sP[4 * g + 0] = make_float4(k0 * a.x, k0 * a.y, k0 * a.z, 0.0f);
    sP[4 * g + 1] = make_float4(k0 * a.w, k0 * bb.x, k0 * bb.y, 0.0f);
    sP[4 * g + 2] = make_float4(k0 * bb.z, k0 * bb.w, k0 * c.x, 0.0f);
    sP[4 * g + 3] = make_float4(k0 * c.y, k0 * c.z, k0 * c.w, 0.0f);
    if (z4) z4[g] = make_float4(0.f, 0.f, 0.f, 0.f);
  }
  __syncthreads();

  const int wave = tid >> 6, lane = tid & 63;
  const int phase = lane >> 1, rg = lane & 1;
  const int r0 = t0 + rg * 8;
  float x1[8], y1[8], z1[8], acc[8];
  load8((const float4*)(xyz1 + (size_t)b * NPTS * 3), r0, k0, x1, y1, z1);
#pragma unroll
  for (int j = 0; j < 8; ++j) acc[j] = 0.0f;
  const int mb = wave * 512 + phase;
#pragma unroll 2
  for (int it = 0; it < 16; ++it) {
    float4 v = sP[mb + it * 32];
#pragma unroll
    for (int j = 0; j < 8; ++j) {
      float dx = x1[j] - v.x, dy = y1[j] - v.y, dz = z1[j] - v.z;
      float s = __builtin_fmaf(dx, dx, __builtin_fmaf(dy, dy, dz * dz));
      acc[j] += fast_exp2(-s);
    }
  }
#pragma unroll
  for (int j = 0; j < 8; ++j) {
    acc[j] += __shfl_xor(acc[j], 2, 64);
    acc[j] += __shfl_xor(acc[j], 4, 64);
    acc[j] += __shfl_xor(acc[j], 8, 64);
    acc[j] += __shfl_xor(acc[j], 16, 64);
    acc[j] += __shfl_xor(acc[j], 32, 64);
  }
  if (lane < 2) {
#pragma unroll
    for (int j = 0; j < 8; ++j) sRed[(rg * 8 + j) * 4 + wave] = acc[j];
  }
  __syncthreads();
  if (tid < ROWS) {
    float s = sRed[tid * 4] + sRed[tid * 4 + 1] + sRed[tid * 4 + 2] +
              sRed[tid * 4 + 3];
    float rs = 1.0f / (s + 1e-9f);
    rowscale[(size_t)b * NPTS + t0 + tid] = rs;
    sRs[tid] = rs;
  }
  __syncthreads();

  float rsn[8];
#pragma unroll
  for (int j = 0; j < 8; ++j) rsn[j] = sRs[rg * 8 + j];
  float* accb = t1acc + ((size_t)(blk & (NSH - 1)) * BATCH + b) * MPTS;
#pragma unroll 2
  for (int it = 0; it < 16; ++it) {
    int idx = mb + it * 32;
    float4 v = sP[idx];
    float part = 0.0f;
#pragma unroll
    for (int j = 0; j < 8; ++j) {
      float dx = x1[j] - v.x, dy = y1[j] - v.y, dz = z1[j] - v.z;
      float s = __builtin_fmaf(dx, dx, __builtin_fmaf(dy, dy, dz * dz));
      part = __builtin_fmaf(fast_exp2(-s), rsn[j], part);
    }
    part += __shfl_xor(part, 1, 64);
    if (rg == 0) atomicAdd(accb + idx, part);
  }
}

// ---------------------------------------------------------------------------
// CA'(l): staging sums the 8 t1 shadow copies + does former B(l) clipping
// elementwise (desig block writes rrOut; blocks blk<8 zero t1Zero copies);
// sweep1 = cost + remainL + rowscale(l+1) (e1 = e2^4); sweep2 atomicAdds
// t1_{l+1} into shadow copy (blk&7). LAST: e1=exp2(-s), t9 += sum rsN.
template <bool FIRST, bool LAST>
__global__ __launch_bounds__(BLOCK, 4) void emd_CA_kernel(
    const float* __restrict__ xyz1, const float* __restrict__ xyz2,
    float* __restrict__ rowscale, float* __restrict__ remainL,
    const float* __restrict__ rrIn, float* __restrict__ rrOut,
    const float* __restrict__ t1In, float* __restrict__ t1Acc,
    float* __restrict__ t1Zero, float* __restrict__ out,
    float* __restrict__ t9, float kS, float invK) {
  __shared__ float4 sP[MPTS];
  __shared__ float sRedS[ROWS * 4];
  __shared__ float sRedC[ROWS * 4];
  __shared__ float sRedR[ROWS * 4];
  __shared__ float sCost[ROWS];
  __shared__ float sRs[ROWS];

  const int tid = threadIdx.x;
  const int bid = blockIdx.x;
  const int b = bid >> 7;
  const int blk = bid & 127;
  const int t0 = blk * ROWS;
  const bool desig = blk == 0;

  const float4* q2 = (const float4*)(xyz2 + (size_t)b * MPTS * 3);
  const float4* rr4 = (const float4*)(rrIn + (size_t)b * MPTS);
  const float4* t14 = (const float4*)(t1In + (size_t)b * MPTS);
  const size_t sh4 = (size_t)BATCH * MPTS / 4;  // copy stride in float4s
  float4* ro4 = (float4*)(rrOut + (size_t)b * MPTS);
  float4* z4 = (!LAST && blk < NSH)
      ? (float4*)(t1Zero + ((size_t)blk * BATCH + b) * MPTS) : nullptr;
  for (int g = tid; g < MPTS / 4; g += BLOCK) {
    float4 a = q2[3 * g], bb = q2[3 * g + 1], c = q2[3 * g + 2];
    float4 t1v = t14[g];
#pragma unroll
    for (int cpy = 1; cpy < NSH; ++cpy) {
      float4 tv = t14[cpy * sh4 + g];
      t1v.x += tv.x; t1v.y += tv.y; t1v.z += tv.z; t1v.w += tv.w;
    }
    float4 rrv = FIRST ? make_float4(1.f, 1.f, 1.f, 1.f) : rr4[g];
    float cc[4], rn[4];
    float rrc[4] = {rrv.x, rrv.y, rrv.z, rrv.w};
    float t1c[4] = {t1v.x, t1v.y, t1v.z, t1v.w};
#pragma unroll
    for (int i = 0; i < 4; ++i) {
      float colsum = rrc[i] * t1c[i];
      float cs = fminf(rrc[i] / (colsum + 1e-9f), 1.0f);
      cc[i] = rrc[i] * cs;
      rn[i] = fmaxf(rrc[i] - colsum * cs, 0.0f);
    }
    sP[4 * g + 0] = make_float4(kS * a.x, kS * a.y, kS * a.z, packh2(cc[0], rn[0]));
    sP[4 * g + 1] = make_float4(kS * a.w, kS * bb.x, kS * bb.y, packh2(cc[1], rn[1]));
    sP[4 * g + 2] = make_float4(kS * bb.z, kS * bb.w, kS * c.x, packh2(cc[2], rn[2]));
    sP[4 * g + 3] = make_float4(kS * c.y, kS * c.z, kS * c.w, packh2(cc[3], rn[3]));
    if (desig) ro4[g] = make_float4(rn[0], rn[1], rn[2], rn[3]);
    if (z4) z4[g] = make_float4(0.f, 0.f, 0.f, 0.f);
  }
  __syncthreads();

  const int wave = tid >> 6, lane = tid & 63;
  const int phase = lane >> 2, rg = lane & 3;
  const int r0 = t0 + rg * 4;
  float x1[4], y1[4], z1[4];
  {
    const float4* q1 = (const float4*)(xyz1 + (size_t)b * NPTS * 3);
    int b4 = (r0 >> 2) * 3;
    float4 a = q1[b4], bb = q1[b4 + 1], c = q1[b4 + 2];
    x1[0] = kS * a.x;  y1[0] = kS * a.y;  z1[0] = kS * a.z;
    x1[1] = kS * a.w;  y1[1] = kS * bb.x; z1[1] = kS * bb.y;
    x1[2] = kS * bb.z; y1[2] = kS * bb.w; z1[2] = kS * c.x;
    x1[3] = kS * c.y;  y1[3] = kS * c.z;  z1[3] = kS * c.w;
  }
  float accS[4] = {0.f, 0.f, 0.f, 0.f};
  float accC[4] = {0.f, 0.f, 0.f, 0.f};
  float accR[4] = {0.f, 0.f, 0.f, 0.f};
  const int mb = wave * 512 + phase;
#pragma unroll 4
  for (int it = 0; it < 32; ++it) {
    float4 v = sP[mb + it * 16];
    __half2 h = __builtin_bit_cast(__half2, v.w);
    float cc = __low2float(h);
    float rr = __high2float(h);
#pragma unroll
    for (int j = 0; j < 4; ++j) {
      float dx = x1[j] - v.x, dy = y1[j] - v.y, dz = z1[j] - v.z;
      float s = __builtin_fmaf(dx, dx, __builtin_fmaf(dy, dy, dz * dz));
      float sq = fast_sqrt(s);
      float e1, e2;
      if (LAST) {
        e2 = 1.0f;
        e1 = fast_exp2(-s);
      } else {
        e2 = fast_exp2(-s);
        float e2s = e2 * e2;
        e1 = e2s * e2s;
      }
      float t = e1 * cc;
      accS[j] += t;
      accC[j] = __builtin_fmaf(t, sq, accC[j]);
      if (LAST) accR[j] += rr;
      else      accR[j] = __builtin_fmaf(e2, rr, accR[j]);
    }
  }
#pragma unroll
  for (int j = 0; j < 4; ++j) {
    accS[j] += __shfl_xor(accS[j], 4, 64);
    accS[j] += __shfl_xor(accS[j], 8, 64);
    accS[j] += __shfl_xor(accS[j], 16, 64);
    accS[j] += __shfl_xor(accS[j], 32, 64);
    accC[j] += __shfl_xor(accC[j], 4, 64);
    accC[j] += __shfl_xor(accC[j], 8, 64);
    accC[j] += __shfl_xor(accC[j], 16, 64);
    accC[j] += __shfl_xor(accC[j], 32, 64);
    accR[j] += __shfl_xor(accR[j], 4, 64);
    accR[j] += __shfl_xor(accR[j], 8, 64);
    accR[j] += __shfl_xor(accR[j], 16, 64);
    accR[j] += __shfl_xor(accR[j], 32, 64);
  }
  if (lane < 4) {
#pragma unroll
    for (int j = 0; j < 4; ++j) {
      sRedS[(rg * 4 + j) * 4 + wave] = accS[j];
      sRedC[(rg * 4 + j) * 4 + wave] = accC[j];
      sRedR[(rg * 4 + j) * 4 + wave] = accR[j];
    }
  }
  __syncthreads();
  if (tid < ROWS) {
    float S2 = sRedS[tid * 4] + sRedS[tid * 4 + 1] + sRedS[tid * 4 + 2] +
               sRedS[tid * 4 + 3];
    float C = sRedC[tid * 4] + sRedC[tid * 4 + 1] + sRedC[tid * 4 + 2] +
              sRedC[tid * 4 + 3];
    float R = sRedR[tid * 4] + sRedR[tid * 4 + 1] + sRedR[tid * 4 + 2] +
              sRedR[tid * 4 + 3];
    size_t idx = (size_t)b * NPTS + t0 + tid;
    float rs = rowscale[idx];
    float rl = FIRST ? 1.0f : remainL[idx];
    float rlN = fmaxf(rl - rs * S2, 0.0f);
    remainL[idx] = rlN;
    float rsN = rlN / (R + 1e-9f);
    rowscale[idx] = rsN;
    sCost[tid] = rs * C * invK;
    sRs[tid] = rsN;
  }
  __syncthreads();
  if (tid == 0) {
    float t = 0.0f;
#pragma unroll
    for (int i = 0; i < ROWS; ++i) t += sCost[i];
    atomicAdd(out + b, t);
    if (LAST) {
      float r = 0.0f;
#pragma unroll
      for (int i = 0; i < ROWS; ++i) r += sRs[i];
      atomicAdd(t9 + b, r);
    }
  }
  if (!LAST) {
    float rsn[4];
#pragma unroll
    for (int j = 0; j < 4; ++j) rsn[j] = sRs[rg * 4 + j];
    float* accb = t1Acc + ((size_t)(blk & (NSH - 1)) * BATCH + b) * MPTS;
#pragma unroll 4
    for (int it = 0; it < 32; ++it) {
      int idx = mb + it * 16;
      float4 v = sP[idx];
      float part = 0.0f;
#pragma unroll
      for (int j = 0; j < 4; ++j) {
        float dx = x1[j] - v.x, dy = y1[j] - v.y, dz = z1[j] - v.z;
        float s = __builtin_fmaf(dx, dx, __builtin_fmaf(dy, dy, dz * dz));
        part = __builtin_fmaf(fast_exp2(-s), rsn[j], part);
      }
      part += __shfl_xor(part, 1, 64);
      part += __shfl_xor(part, 2, 64);
      if (rg == 0) atomicAdd(accb + idx, part);
    }
  }
}

// ---------------------------------------------------------------------------
// C9 (lvl=0): t1 = t9[b]; colcoef during staging; cost += rs * sum cc*sqrt(d2).
__global__ __launch_bounds__(BLOCK, 4) void emd_C9_kernel(
    const float* __restrict__ xyz1, const float* __restrict__ xyz2,
    const float* __restrict__ rowscale, const float* __restrict__ remainR,
    const float* __restrict__ t9, float* __restrict__ out) {
  __shared__ float4 sP[MPTS];
  __shared__ float sRed[ROWS * 4];
  __shared__ float sCost[ROWS];

  const int tid = threadIdx.x;
  const int bid = blockIdx.x;
  const int b = bid >> 7;
  const int t0 = (bid & 127) * ROWS;
  const int wave = tid >> 6, lane = tid & 63;
  const float t1 = t9[b];

  const float4* q2 = (const float4*)(xyz2 + (size_t)b * MPTS * 3);
  const float4* rr4 = (const float4*)(remainR + (size_t)b * MPTS);
  for (int g = tid; g < MPTS / 4; g += BLOCK) {
    float4 a = q2[3 * g], bb = q2[3 * g + 1], c = q2[3 * g + 2];
    float4 rr = rr4[g];
    float w0 = rr.x * fminf(rr.x / (rr.x * t1 + 1e-9f), 1.0f);
    float w1 = rr.y * fminf(rr.y / (rr.y * t1 + 1e-9f), 1.0f);
    float w2 = rr.z * fminf(rr.z / (rr.z * t1 + 1e-9f), 1.0f);
    float w3 = rr.w * fminf(rr.w / (rr.w * t1 + 1e-9f), 1.0f);
    sP[4 * g + 0] = make_float4(a.x, a.y, a.z, w0);
    sP[4 * g + 1] = make_float4(a.w, bb.x, bb.y, w1);
    sP[4 * g + 2] = make_float4(bb.z, bb.w, c.x, w2);
    sP[4 * g + 3] = make_float4(c.y, c.z, c.w, w3);
  }
  __syncthreads();

  const int phase = lane >> 1, rg = lane & 1;
  const int r0 = t0 + rg * 8;
  float x1[8], y1[8], z1[8], acc[8];
  load8((const float4*)(xyz1 + (size_t)b * NPTS * 3), r0, 1.0f, x1, y1, z1);
#pragma unroll
  for (int j = 0; j < 8; ++j) acc[j] = 0.0f;
  const int mb = wave * 512 + phase;
#pragma unroll 2
  for (int it = 0; it < 16; ++it) {
    float4 v = sP[mb + it * 32];
#pragma unroll
    for (int j = 0; j < 8; ++j) {
      float dx = x1[j] - v.x, dy = y1[j] - v.y, dz = z1[j] - v.z;
      float d2 = __builtin_fmaf(dx, dx, __builtin_fmaf(dy, dy, dz * dz));
      acc[j] = __builtin_fmaf(fast_sqrt(d2), v.w, acc[j]);
    }
  }
#pragma unroll
  for (int j = 0; j < 8; ++j) {
    acc[j] += __shfl_xor(acc[j], 2, 64);
    acc[j] += __shfl_xor(acc[j], 4, 64);
    acc[j] += __shfl_xor(acc[j], 8, 64);
    acc[j] += __shfl_xor(acc[j], 16, 64);
    acc[j] += __shfl_xor(acc[j], 32, 64);
  }
  if (lane < 2) {
#pragma unroll
    for (int j = 0; j < 8; ++j) sRed[(rg * 8 + j) * 4 + wave] = acc[j];
  }
  __syncthreads();
  if (tid < ROWS) {
    float C = sRed[tid * 4] + sRed[tid * 4 + 1] + sRed[tid * 4 + 2] +
              sRed[tid * 4 + 3];
    sCost[tid] = rowscale[(size_t)b * NPTS + t0 + tid] * C;
  }
  __syncthreads();
  if (tid == 0) {
    float t = 0.0f;
#pragma unroll
    for (int i = 0; i < ROWS; ++i) t += sCost[i];
    atomicAdd(out + b, t);
  }
}

// ---------------------------------------------------------------------------
extern "C" void kernel_launch(void* const* d_in, const int* in_sizes, int n_in,
                              void* d_out, int out_size, void* d_ws, size_t ws_size,
                              hipStream_t stream) {
  const float* xyz1 = (const float*)d_in[0];
  const float* xyz2 = (const float*)d_in[1];
  float* out = (float*)d_out;
  float* ws = (float*)d_ws;

  const int BN = BATCH * NPTS, BM = BATCH * MPTS;
  const size_t TBUF = (size_t)NSH * BM;  // one t1 buffer (8 shadow copies)
  float* remainL  = ws;                    // BN
  float* rowscale = ws + BN;               // BN
  float* rrA      = ws + 2 * BN;           // BM
  float* rrB      = ws + 2 * BN + BM;      // BM
  float* t1b      = ws + 2 * BN + 2 * BM;  // 3 * TBUF
  float* t9       = ws + 2 * BN + 2 * BM + 3 * TBUF;  // BATCH

  const float levels[9] = {-16384.f, -4096.f, -1024.f, -256.f, -64.f,
                           -16.f,    -4.f,    -1.f,    -0.25f};
  dim3 grid(BATCH * (NPTS / ROWS));  // 1024 blocks

  hipMemsetAsync(t1b, 0, TBUF * sizeof(float), stream);  // zero buf0

  emd_A0_kernel<<<grid, BLOCK, 0, stream>>>(
      xyz1, xyz2, rowscale, out, t9, t1b /*acc=buf0*/, t1b + TBUF /*zero=buf1*/,
      sqrtf(-levels[0] * LOG2E));

  for (int l = 0; l < 9; ++l) {
    float kB = sqrtf(-levels[l] * LOG2E);
    float kA = 0.5f * kB;
    float* cur = t1b + (size_t)(l % 3) * TBUF;
    float* nxt = t1b + (size_t)((l + 1) % 3) * TBUF;
    float* zer = t1b + (size_t)((l + 2) % 3) * TBUF;
    float* rin = (l % 2 == 0) ? rrA : rrB;  // unused for l==0
    float* rou = (l % 2 == 0) ? rrB : rrA;
    if (l == 0) {
      emd_CA_kernel<true, false><<<grid, BLOCK, 0, stream>>>(
          xyz1, xyz2, rowscale, remainL, rin, rou, cur, nxt, zer, out, t9,
          kA, 1.0f / kA);
    } else if (l < 8) {
      emd_CA_kernel<false, false><<<grid, BLOCK, 0, stream>>>(
          xyz1, xyz2, rowscale, remainL, rin, rou, cur, nxt, zer, out, t9,
          kA, 1.0f / kA);
    } else {
      emd_CA_kernel<false, true><<<grid, BLOCK, 0, stream>>>(
          xyz1, xyz2, rowscale, remainL, rin, rou, cur, nxt, zer, out, t9,
          kB, 1.0f / kB);
    }
  }
  // rr_9 in rrB (l=8 even). t1_9 scalar in t9.
  emd_C9_kernel<<<grid, BLOCK, 0, stream>>>(xyz1, xyz2, rowscale, rrB, t9, out);
}